// Round 9
// baseline (19086.079 us; speedup 1.0000x reference)
//
#include <hip/hip_runtime.h>

// VQ forward on MI355X — round 18: barrier-free coarse main loop (R17
// resubmit; R17 hit an infra container failure, audit found no kernel
// defect — OOB/deadlock/gld16-contract all verified clean).
// x: [32768,512] fp32, codebook: [8192,512] fp32.
// d_out (fp32): [16.7M) quantized_st | [1] vq_loss | [32768] idx-as-float
//
// Design (from R16 post-mortem): cost was 64 lockstep vmcnt(0)+barrier
// drains per block (~4220cy/step vs ~620cy MFMA). This version removes ALL
// main-loop synchronization:
//   - A (64 rows x K=512, 64KB) resident in LDS, staged ONCE via gld16
//     (R14 conflict-free swizzle: 16B slot s stored at s^(r&7), source
//     pre-swizzled). A-restage traffic 2GB -> 128MB.
//   - B streamed global->registers: prep writes the codebook in
//     MFMA-fragment-linear layout (panel = 32 codes; chunk (ks,ct) =
//     64 lanes x 16B, lane (q*16+l15) holds code ct*16+l15, k =
//     ks*32+q*8+e — byte-identical VALUES to the old LDS fragment read).
//     Per (wave,ci) one contiguous 32KB panel, fully coalesced, compiler
//     pipelines freely (no barriers). XCD-pinned: 2MB quarter L2-resident.
//   - Per-wave screen: running row-min in regs, per-wave LDS segment
//     lists (wave-local atomics). One end-of-block merge rebuilds R16's
//     exact output format (4 quarter segments/row) -> rescore UNCHANGED.
// 8 waves/block (512thr), wave tile 64x32, acc[4][2]=32 regs,
// launch_bounds(512,4) targets <=128 VGPR -> 2 blocks/CU.
// MFMA inputs and k-order bit-identical per (row,code) -> screen distances
// bit-identical; per-wave prefix-min partitioning preserves the
// argmin+ties superset invariant (runningMin_w >= quarterMin so every code
// within quarterMin+MARGIN is appended); quarter bmin = min of 8 wave-mins
// = same value as R16. Overflow -> cnt 25 -> exact quarter scan. Outputs
// bit-identical (absmax 0 since R1).

#define NROWS 32768
#define KCODES 8192
#define DD 512
#define CAP 24
#define LCAP 8
#define MARGIN 2.5e-4f

typedef __bf16 bf16_t;
typedef __bf16 bf16x8 __attribute__((ext_vector_type(8)));
typedef float f32x4 __attribute__((ext_vector_type(4)));

__device__ __forceinline__ void gld16(const bf16_t* g, bf16_t* l) {
  __builtin_amdgcn_global_load_lds(
      (const __attribute__((address_space(1))) void*)g,
      (__attribute__((address_space(3))) void*)l, 16, 0, 0);
}

// ---------------- fused prep for BOTH inputs: per-row sum of fp32 squares
// (fp64 accumulate, fp32 round — order identical since R9) + bf16 convert.
// x -> row-major xbf; codebook -> fragment-linear cbfrag:
//   panel = code>>5 (32 codes), chunk (ks = k>>5, ct = (code>>4)&1),
//   lane-slot (q = (k&31)>>3)*16 + (code&15), 8 elems (k&7).
__global__ __launch_bounds__(256) void prep_kernel(
    const float* __restrict__ x, const float* __restrict__ cb,
    float* __restrict__ xsq, float* __restrict__ csq,
    bf16_t* __restrict__ xbf, bf16_t* __restrict__ cbfrag) {
  const int wave = threadIdx.x >> 6;
  const int lane = threadIdx.x & 63;
  const bool iscb = blockIdx.x < KCODES / 4;
  const float* in;
  float* osq;
  int row;
  if (iscb) {
    in = cb; osq = csq;
    row = blockIdx.x * 4 + wave;
  } else {
    in = x; osq = xsq;
    row = (blockIdx.x - KCODES / 4) * 4 + wave;
  }
  const float* p = in + (size_t)row * DD;
  double s = 0.0;
#pragma unroll
  for (int j = 0; j < DD / 64; ++j) {
    float v = p[j * 64 + lane];
    float sq = v * v;
    s += (double)sq;
  }
  for (int off = 32; off > 0; off >>= 1) s += __shfl_down(s, off, 64);
  if (lane == 0) osq[row] = (float)s;
  const float4* p4 = (const float4*)p;
  float4 a = p4[lane * 2];
  float4 b = p4[lane * 2 + 1];
  bf16x8 o = {(bf16_t)a.x, (bf16_t)a.y, (bf16_t)a.z, (bf16_t)a.w,
              (bf16_t)b.x, (bf16_t)b.y, (bf16_t)b.z, (bf16_t)b.w};
  if (iscb) {
    const int panel = row >> 5, ct = (row >> 4) & 1, cl = row & 15;
    const int ks = lane >> 2, qq = lane & 3;
    *(bf16x8*)(cbfrag + (size_t)panel * 16384 + (ks * 2 + ct) * 512 +
               (qq * 16 + cl) * 8) = o;
  } else {
    *(bf16x8*)(xbf + (size_t)row * DD + lane * 8) = o;
  }
}

// ---------------- coarse: barrier-free MFMA GEMM + per-wave margin screen.
// Block: 64 rows x quarter (2048 codes); 8 waves, each 64 rows x 32 codes
// per 256-code ci-tile. acc[4][2]. A in LDS full-K; B global fragments.
__global__ __launch_bounds__(512, 4) void coarse_kernel(
    const bf16_t* __restrict__ xbf, const bf16_t* __restrict__ cbfrag,
    const float* __restrict__ csq, unsigned char* __restrict__ cnt_g,
    unsigned short* __restrict__ list_g, unsigned* __restrict__ bmin_g) {
  __shared__ bf16_t As[64 * 512];               // 64 KB, swizzled full-K A
  __shared__ unsigned short lseg[8][64][LCAP];  // 8 KB per-wave lists
  __shared__ int lcnt[8][64];                   // 2 KB
  __shared__ unsigned wmin[8][64];              // 2 KB

  const int tid = threadIdx.x;
  const int w = tid >> 6;            // col-group 0..7 (wave id)
  const int lane = tid & 63;
  const int q = lane >> 4;
  const int l15 = lane & 15;
  const int rm = l15 & 7;

  // XCD-aware decode (grid 2048 % 8 == 0): XCD pair owns one quarter
  // (2MB fragment layout, L2-resident); row-blocks contiguous per XCD.
  const int bid = blockIdx.x;
  const int xcd = bid & 7;
  const int g = bid >> 3;                    // 0..255
  const int qtr = xcd >> 1;                  // 0..3
  const int rowblk = (xcd & 1) * 256 + g;    // 0..511, bijective
  const int row0 = rowblk * 64;
  const int cbase = qtr * (KCODES / 4);

  for (int i = tid; i < 8 * 64; i += 512) ((int*)lcnt)[i] = 0;

  // ---- A stage (once): 8 gld16 calls, 512 thr x 16B = 8KB = 8 rows/call.
  // r = j*8 + (tid>>6), stored slot tid&63, LDS dest linear = j*4096+tid*8.
  // Source slot sg = (tid&63) ^ (r&7); r&7 = tid>>6 (j*8 == 0 mod 8).
  {
    const int sg = (tid & 63) ^ (tid >> 6);
    const bf16_t* aG = xbf + (size_t)(row0 + (tid >> 6)) * DD + sg * 8;
    bf16_t* aL = As + tid * 8;
#pragma unroll
    for (int j = 0; j < 8; ++j) gld16(aG + j * 4096, aL + j * 4096);
  }
  __syncthreads();   // A ready + lcnt init visible. LAST barrier before merge.

  float bestr[4][4];
#pragma unroll
  for (int rt = 0; rt < 4; ++rt)
#pragma unroll
    for (int reg = 0; reg < 4; ++reg) bestr[rt][reg] = 1e30f;

  // A fragment row bases (elements): row = rt*16 + l15, stride 512.
  int arb[4];
#pragma unroll
  for (int rt = 0; rt < 4; ++rt) arb[rt] = (rt * 16 + l15) * 512;

#pragma unroll 1
  for (int ci = 0; ci < 8; ++ci) {           // 8 tiles of 256 codes
    const int c0 = cbase + ci * 256 + w * 32;   // wave's 32-code column base
    const bf16_t* bp = cbfrag + (size_t)(qtr * 64 + ci * 8 + w) * 16384;

    f32x4 acc[4][2];
#pragma unroll
    for (int rt = 0; rt < 4; ++rt)
#pragma unroll
      for (int ct = 0; ct < 2; ++ct) {
        f32x4 z = {0.f, 0.f, 0.f, 0.f};
        acc[rt][ct] = z;
      }

#pragma unroll 4
    for (int ks = 0; ks < 16; ++ks) {        // ascending k, 32 per substep
      bf16x8 b0 = *(const bf16x8*)(bp + (ks * 2 + 0) * 512 + lane * 8);
      bf16x8 b1 = *(const bf16x8*)(bp + (ks * 2 + 1) * 512 + lane * 8);
      bf16x8 af[4];
#pragma unroll
      for (int rt = 0; rt < 4; ++rt)
        af[rt] = *(const bf16x8*)&As[arb[rt] + (((ks * 4 + q) ^ rm) << 3)];
#pragma unroll
      for (int rt = 0; rt < 4; ++rt) {
        acc[rt][0] = __builtin_amdgcn_mfma_f32_16x16x32_bf16(
            af[rt], b0, acc[rt][0], 0, 0, 0);
        acc[rt][1] = __builtin_amdgcn_mfma_f32_16x16x32_bf16(
            af[rt], b1, acc[rt][1], 0, 0, 0);
      }
    }

    // ---- per-wave screen (no barriers). d' = 1 + csq - 2*dot (>0).
    const float csA = 1.0f + csq[c0 + l15];
    const float csB = 1.0f + csq[c0 + 16 + l15];
#pragma unroll
    for (int rt = 0; rt < 4; ++rt) {
#pragma unroll
      for (int reg = 0; reg < 4; ++reg) {
        const float d0 = fmaf(-2.0f, acc[rt][0][reg], csA);
        const float d1 = fmaf(-2.0f, acc[rt][1][reg], csB);
        float m = fminf(d0, d1);
#pragma unroll
        for (int msk = 1; msk <= 8; msk <<= 1)
          m = fminf(m, __shfl_xor(m, msk, 64));
        // running prefix-min for this wave's column slice (incl. this tile)
        const float nb = fminf(bestr[rt][reg], m);
        bestr[rt][reg] = nb;
        const float thr = nb + MARGIN;
        const int ridx = rt * 16 + q * 4 + reg;
        if (d0 <= thr) {
          int p = atomicAdd(&lcnt[w][ridx], 1);
          if (p < LCAP) lseg[w][ridx][p] = (unsigned short)(c0 + l15);
        }
        if (d1 <= thr) {
          int p = atomicAdd(&lcnt[w][ridx], 1);
          if (p < LCAP) lseg[w][ridx][p] = (unsigned short)(c0 + 16 + l15);
        }
      }
    }
  }

  // publish per-wave row mins (all l15 lanes hold them; l15==0 writes)
#pragma unroll
  for (int rt = 0; rt < 4; ++rt)
#pragma unroll
    for (int reg = 0; reg < 4; ++reg)
      if (l15 == 0)
        wmin[w][rt * 16 + q * 4 + reg] = __float_as_uint(bestr[rt][reg]);

  __syncthreads();

  // ---- merge 8 wave segments per row -> R16 output format (4 seg/row).
  if (tid < 64) {
    const int row = tid;
    const size_t obase = ((size_t)(row0 + row) * 4 + qtr);
    int total = 0;
    bool of = false;
    unsigned bm = 0xFFFFFFFFu;
#pragma unroll
    for (int w2 = 0; w2 < 8; ++w2) {
      bm = min(bm, wmin[w2][row]);
      int c = lcnt[w2][row];
      if (c > LCAP) { of = true; c = LCAP; }
      for (int j = 0; j < c; ++j) {
        if (total < CAP) list_g[obase * CAP + total] = lseg[w2][row][j];
        ++total;
      }
    }
    cnt_g[obase] = (unsigned char)((of || total > CAP) ? CAP + 1 : total);
    bmin_g[obase] = bm;
  }
}

// ---------------- exact distance, R1's bit-exact fmaf chain (both paths)
__device__ __forceinline__ float exact_dist(const float4* __restrict__ xr4,
                                            const float* __restrict__ cb,
                                            const float* __restrict__ csq,
                                            float xs, int idx) {
  const float4* cr4 = (const float4*)(cb + (size_t)idx * DD);
  float acc = 0.0f;
  for (int k4 = 0; k4 < DD / 4; ++k4) {     // sequential ascending k: R1 order
    float4 xv = xr4[k4];
    float4 cv = cr4[k4];
    acc = fmaf(xv.x, cv.x, acc);
    acc = fmaf(xv.y, cv.y, acc);
    acc = fmaf(xv.z, cv.z, acc);
    acc = fmaf(xv.w, cv.w, acc);
  }
  float t = xs - 2.0f * acc;
  return t + csq[idx];
}

// ---------------- phase 2 fused: exact rescore + straight-through gather +
// loss partial + idx-as-float. One wave per row. Quarters with qmin >
// gmin+MARGIN cannot hold the argmin or any exact tie -> skipped.
// Overflowed RELEVANT quarters exactly scanned (2048 codes).
__global__ __launch_bounds__(256) void rescore_epilogue_kernel(
    const float* __restrict__ x, const float* __restrict__ cb,
    const float* __restrict__ xsq, const float* __restrict__ csq,
    const unsigned short* __restrict__ list,
    const unsigned char* __restrict__ cnt, const unsigned* __restrict__ bmin,
    float* __restrict__ out_q, float* __restrict__ out_idx_f,
    double* __restrict__ partials) {
  const int row = blockIdx.x * 4 + (threadIdx.x >> 6);
  const int lane = threadIdx.x & 63;
  const unsigned char* c4 = cnt + (size_t)row * 4;
  const unsigned* bm4 = bmin + (size_t)row * 4;
  const float xs = xsq[row];
  const float4* xr4 = (const float4*)(x + (size_t)row * DD);

  float qm[4];
  int n[4];
#pragma unroll
  for (int s = 0; s < 4; ++s) {
    qm[s] = __uint_as_float(bm4[s]);
    n[s] = c4[s];
  }
  const float gmin = fminf(fminf(qm[0], qm[1]), fminf(qm[2], qm[3]));
  const float cut = gmin + MARGIN;
  bool listed[4], scanq[4];
  int L = 0;
#pragma unroll
  for (int s = 0; s < 4; ++s) {
    const bool rel = (qm[s] <= cut);
    listed[s] = rel && (n[s] <= CAP);
    scanq[s] = rel && (n[s] > CAP);
    if (listed[s]) L += n[s];
  }
  if (L > 64) {   // pathological: exact-scan every relevant quarter
#pragma unroll
    for (int s = 0; s < 4; ++s)
      if (listed[s]) { listed[s] = false; scanq[s] = true; }
    L = 0;
  }

  unsigned long long bestv = ~0ULL;

  // listed candidates from relevant healthy quarters (lane-parallel, <=64)
  int myidx = -1;
  int base = 0;
#pragma unroll
  for (int s = 0; s < 4; ++s) {
    if (listed[s]) {
      if (myidx < 0 && lane >= base && lane < base + n[s])
        myidx = (int)list[((size_t)row * 4 + s) * CAP + (lane - base)];
      base += n[s];
    }
  }
  if (myidx >= 0) {
    float d = exact_dist(xr4, cb, csq, xs, myidx);
    bestv = ((unsigned long long)__float_as_uint(d) << 32) | (unsigned)myidx;
  }

  // relevant overflowed quarters: exact lane-strided scan of that quarter
#pragma unroll
  for (int s = 0; s < 4; ++s) {
    if (scanq[s]) {
      const int q0 = s * (KCODES / 4);
      for (int idx = q0 + lane; idx < q0 + KCODES / 4; idx += 64) {
        float d = exact_dist(xr4, cb, csq, xs, idx);
        unsigned long long pk =
            ((unsigned long long)__float_as_uint(d) << 32) | (unsigned)idx;
        if (pk < bestv) bestv = pk;
      }
    }
  }

#pragma unroll
  for (int s = 1; s <= 32; s <<= 1) {
    unsigned long long o = __shfl_xor(bestv, s, 64);
    if (o < bestv) bestv = o;
  }
  const int k = (int)(bestv & 0xffffffffu);

  // ---- fused epilogue. Bit-exact replica of the old 128-thread kernel:
  // lane handles float4 #lane (old wave0 thread) and #lane+64 (old wave1),
  // reduced as two independent 64-lane shuffle trees, summed at the end.
  const float4* qr = (const float4*)(cb + (size_t)k * DD);
  float4* orow = (float4*)(out_q + (size_t)row * DD);

  float4 xa = xr4[lane], qa = qr[lane];
  float dax = qa.x - xa.x, day = qa.y - xa.y, daz = qa.z - xa.z, daw = qa.w - xa.w;
  float4 oa;
  oa.x = xa.x + dax; oa.y = xa.y + day; oa.z = xa.z + daz; oa.w = xa.w + daw;
  orow[lane] = oa;
  double pa = (double)(dax * dax) + (double)(day * day) +
              (double)(daz * daz) + (double)(daw * daw);

  float4 xb = xr4[lane + 64], qb = qr[lane + 64];
  float dbx = qb.x - xb.x, dby = qb.y - xb.y, dbz = qb.z - xb.z, dbw = qb.w - xb.w;
  float4 ob;
  ob.x = xb.x + dbx; ob.y = xb.y + dby; ob.z = xb.z + dbz; ob.w = xb.w + dbw;
  orow[lane + 64] = ob;
  double pb = (double)(dbx * dbx) + (double)(dby * dby) +
              (double)(dbz * dbz) + (double)(dbw * dbw);

  for (int off = 32; off > 0; off >>= 1) pa += __shfl_down(pa, off, 64);
  for (int off = 32; off > 0; off >>= 1) pb += __shfl_down(pb, off, 64);
  if (lane == 0) {
    partials[row] = pa + pb;
    out_idx_f[row] = (float)k;
  }
}

// ---------------- reduce partials -> vq_loss
__global__ __launch_bounds__(256) void finalize_kernel(
    const double* __restrict__ partials, float* __restrict__ out_loss) {
  __shared__ double red[256];
  double s = 0.0;
  for (int i = threadIdx.x; i < NROWS; i += 256) s += partials[i];
  red[threadIdx.x] = s;
  __syncthreads();
  for (int st = 128; st > 0; st >>= 1) {
    if (threadIdx.x < st) red[threadIdx.x] += red[threadIdx.x + st];
    __syncthreads();
  }
  if (threadIdx.x == 0) {
    double mean = red[0] / ((double)NROWS * (double)DD);
    float cl = (float)mean;
    out_loss[0] = cl + 0.25f * cl;
  }
}

extern "C" void kernel_launch(void* const* d_in, const int* in_sizes, int n_in,
                              void* d_out, int out_size, void* d_ws,
                              size_t ws_size, hipStream_t stream) {
  const float* x = (const float*)d_in[0];
  const float* cb = (const float*)d_in[1];
  float* out = (float*)d_out;

  // ws layout: partials | csq | xsq | cnt(u8,4/row) | bmin(u32,4/row) | list
  char* ws = (char*)d_ws;
  double* partials = (double*)ws;                               // 262144 B
  float* csq = (float*)(ws + 262144);                           //  32768 B
  float* xsq = (float*)(ws + 262144 + 32768);                   // 131072 B
  unsigned char* cnt = (unsigned char*)(ws + 262144 + 32768 + 131072); // 131072 B
  unsigned* bmin = (unsigned*)(ws + 262144 + 32768 + 131072 + 131072); // 524288 B
  unsigned short* list =
      (unsigned short*)(ws + 262144 + 32768 + 131072 + 131072 + 524288); // 6.3 MB

  // bf16 copies live in d_out scratch (overwritten by fused epilogue later)
  bf16_t* cbfrag = (bf16_t*)d_out;
  bf16_t* xbf = cbfrag + (size_t)KCODES * DD;

  prep_kernel<<<(KCODES + NROWS) / 4, 256, 0, stream>>>(x, cb, xsq, csq,
                                                        xbf, cbfrag);
  coarse_kernel<<<2048, 512, 0, stream>>>(xbf, cbfrag, csq, cnt, list, bmin);
  rescore_epilogue_kernel<<<NROWS / 4, 256, 0, stream>>>(
      x, cb, xsq, csq, list, cnt, bmin, out, out + 16777216 + 1, partials);
  finalize_kernel<<<1, 256, 0, stream>>>(partials, out + 16777216);
}